// Round 7
// baseline (375.383 us; speedup 1.0000x reference)
//
#include <hip/hip_runtime.h>
#include <stdint.h>

#define Bn 2
#define Nn 30000
#define En 120000
#define KIN 512
#define Hh 4
#define Dd 128
#define MROWS 60000            // B*N rows
#define MPAD  60032            // 938 * 64
#define LNEPS 1e-5f
#define EBLK 469               // ceil(En/256)

typedef unsigned short u16;
typedef unsigned int   u32;
typedef __attribute__((ext_vector_type(8))) short short8;
typedef __attribute__((ext_vector_type(4))) short bf16x4;
typedef __attribute__((ext_vector_type(4))) float f32x4;

__device__ __forceinline__ u16 f2bf(float f) {
    u32 u = __builtin_bit_cast(u32, f);
    u32 r = u + 0x7FFFu + ((u >> 16) & 1u);
    return (u16)(r >> 16);
}
__device__ __forceinline__ float bflo(u32 u) {
    return __builtin_bit_cast(float, u << 16);
}
__device__ __forceinline__ float bfhi(u32 u) {
    return __builtin_bit_cast(float, u & 0xFFFF0000u);
}
__device__ __forceinline__ void ld16(void* lds, const void* g) {
    __builtin_amdgcn_global_load_lds((const __attribute__((address_space(1))) void*)g,
                                     (__attribute__((address_space(3))) void*)lds, 16, 0, 0);
}

// ---- kernel 1: prep = cvt_w (1024 blocks) + hist (469) ----
#define CVTW_BLKS 1024         // 512*512/256 exactly
__global__ void prep_kernel(const float* __restrict__ W, u16* __restrict__ wbt,
                            const int* __restrict__ ei, int* __restrict__ deg) {
    int blk = blockIdx.x;
    if (blk < CVTW_BLKS) {
        int idx = blk * 256 + threadIdx.x;
        int c = idx >> 9, i = idx & 511;
        int h = c >> 7, d = c & 127;
        wbt[idx] = f2bf(W[h * (KIN * Dd) + i * Dd + d]);
    } else {
        int e = (blk - CVTW_BLKS) * 256 + threadIdx.x;
        if (e < En) atomicAdd(&deg[ei[En + e]], 1);
    }
}

// ---- scan as a device function: 512 threads, exclusive scan of deg[30000].
//      part[] reuses the gemm's LDS block. ----
__device__ void scan512(const int* __restrict__ deg, int* __restrict__ offs,
                        int* __restrict__ cursor, int* __restrict__ part) {
    int tid = threadIdx.x;
    const int CH = 59;                 // 512*59 = 30208 >= Nn
    int start = tid * CH;
    int s = 0;
    for (int i = 0; i < CH; i++) {
        int n = start + i;
        if (n < Nn) s += deg[n];
    }
    part[tid] = s;
    __syncthreads();
    for (int off = 1; off < 512; off <<= 1) {
        int xv = (tid >= off) ? part[tid - off] : 0;
        __syncthreads();
        part[tid] += xv;
        __syncthreads();
    }
    int run = part[tid] - s;
    for (int i = 0; i < CH; i++) {
        int n = start + i;
        if (n < Nn) {
            offs[n] = run;
            cursor[n] = run;
            run += deg[n];
        }
    }
    if (tid == 511) offs[Nn] = part[511];
}

// ---- kernel 2: GEMM t = x(f32) * wbt^T, fused cvt, BM=64 LOW-REG tile.
//      THEORY (r6 post-mortem): previous acc[4][8]=128 AGPR + 116 VGPR = 244
//      regs/wave -> 2 waves/SIMD -> ONE block/CU -> per-step vmcnt(0)+barrier
//      has zero cross-block overlap (m233 stall at full force). This tile:
//      acc[4][4]=64 AGPR, K-loop VGPR ~60, __launch_bounds__(512,4) ->
//      <=128 regs -> TWO blocks/CU (16 waves/CU) -> barriers interleave (m114).
//      8 waves: wave w -> rows 0..63, cols w*64..+63 (head w>>1, half-head).
//      72 KB LDS (x2 = 144 <= 160). s1/s2 via LDS half-head combine. ----
#define A_LDSU 4096            // u16: 2 * 64*32
#define B_LDSU 32768           // u16: 2 * 512*32
__launch_bounds__(512, 4)
__global__ void gemm(const float* __restrict__ x, const u16* __restrict__ wbt,
                     const float* __restrict__ ag, u16* __restrict__ t,
                     float* __restrict__ s1g, float* __restrict__ s2g,
                     const int* __restrict__ deg, int* __restrict__ offs,
                     int* __restrict__ cursor) {
    __shared__ __align__(16) u16 smem[A_LDSU + B_LDSU];   // 72 KB
    if (blockIdx.x == 0) { scan512(deg, offs, cursor, (int*)smem); return; }
    u16* As0 = smem;
    u16* As1 = smem + 2048;
    u16* Bs0 = smem + A_LDSU;
    u16* Bs1 = smem + A_LDSU + 16384;
    const int tid = threadIdx.x;
    const int m0 = (blockIdx.x - 1) * 64;           // tiles 0..937 (= MPAD rows)
    const int w = tid >> 6, l = tid & 63;
    const int lr = l & 15, lk = l >> 4;
    const int h = w >> 1;                           // head (2 waves share one)
    const int wc = w * 64;                          // wave col base (of 512)
    // swizzled ds_read offsets (u16 units): byte ^= ((row&6)<<3) on the 16B slot
    const int swz = (lk * 8) ^ ((lr & 6) << 2);
    int aoff[4], boff[4];
    #pragma unroll
    for (int mi = 0; mi < 4; mi++) aoff[mi] = (mi * 16 + lr) * 32 + swz;
    #pragma unroll
    for (int nj = 0; nj < 4; nj++) boff[nj] = (wc + nj * 16 + lr) * 32 + swz;

    // A source: thread covers row = tid>>3 (clamped), k-chunk = tid&7 (4 f32)
    const int arow_u = m0 + (tid >> 3);
    const int arow = arow_u < MROWS ? arow_u : (MROWS - 1);   // pad-row clamp
    const float* xsrc = x + (long)arow * KIN + (tid & 7) * 4;
    // swizzled A ds_write address (u16 units), constant across steps (8B write)
    const int awr = (tid >> 3) * 32 + (((tid & 7) * 4) ^ (((tid >> 3) & 6) << 2));

    // B source: pre-swizzled global (inverse of read swizzle; involution)
    const int grow = tid >> 2, gslot = tid & 3;
    const int gsw = (gslot * 8) ^ ((grow & 6) << 2);
    const u16* bgsrc = wbt + (long)grow * KIN + gsw;   // chunk i rows = i*128+grow
    f32x4 acc[4][4] = {};
    float4 rxA, rxB;                                   // 2 static x-reg sets

#define LOADX(R, KS)  { R = *(const float4*)(xsrc + (KS) * 32); }
#define CVTW(BUF, R)                                                \
    {                                                               \
        bf16x4 o;                                                   \
        o[0] = (short)f2bf(R.x); o[1] = (short)f2bf(R.y);           \
        o[2] = (short)f2bf(R.z); o[3] = (short)f2bf(R.w);           \
        *(bf16x4*)&(BUF)[awr] = o;                                  \
    }

    auto STAGEB = [&](u16* Bb, int k0) {
        #pragma unroll
        for (int i = 0; i < 4; i++)
            ld16(Bb + ((long)(i * 512 + tid)) * 8, bgsrc + (long)i * 128 * KIN + k0);
    };

    // prologue
    LOADX(rxA, 0);
    LOADX(rxB, 1);
    STAGEB(Bs0, 0);
    CVTW(As0, rxA);
    __syncthreads();

    #pragma unroll
    for (int t16 = 0; t16 < 16; t16++) {
        u16* Acur = (t16 & 1) ? As1 : As0;
        u16* Bcur = (t16 & 1) ? Bs1 : Bs0;
        u16* Anext = (t16 & 1) ? As0 : As1;
        u16* Bnext = (t16 & 1) ? Bs0 : Bs1;
        if (t16 < 14) {                     // x(t+2) into the just-freed set
            if (t16 & 1) { LOADX(rxB, t16 + 2); }
            else         { LOADX(rxA, t16 + 2); }
        }
        if (t16 < 15) STAGEB(Bnext, (t16 + 1) * 32);
        short8 af[4];
        #pragma unroll
        for (int mi = 0; mi < 4; mi++) af[mi] = *(const short8*)&Acur[aoff[mi]];
        #pragma unroll
        for (int nj = 0; nj < 4; nj++) {
            short8 bv = *(const short8*)&Bcur[boff[nj]];
            #pragma unroll
            for (int mi = 0; mi < 4; mi++)
                acc[mi][nj] = __builtin_amdgcn_mfma_f32_16x16x32_bf16(
                    af[mi], bv, acc[mi][nj], 0, 0, 0);
        }
        if (t16 < 15) {                     // write A(t+1) from set ((t+1)&1)
            if (t16 & 1) { CVTW(Anext, rxA); }
            else         { CVTW(Anext, rxB); }
        }
        __syncthreads();    // drains staging + protects buffer reuse
    }
#undef LOADX
#undef CVTW

    // C/D map: col = wc + nj*16 + lr, row = mi*16 + lk*4 + r
    #pragma unroll
    for (int mi = 0; mi < 4; mi++)
        #pragma unroll
        for (int r = 0; r < 4; r++) {
            int row = m0 + mi * 16 + lk * 4 + r;
            u16* tp = t + (long)row * 512 + wc + lr;
            #pragma unroll
            for (int nj = 0; nj < 4; nj++)
                tp[nj * 16] = f2bf(acc[mi][nj][r]);
        }
    // ---- fused s1/s2: wave covers HALF a head (cols (w&1)*64 .. +63) ----
    float a1c[4], a2c[4];
    #pragma unroll
    for (int nj = 0; nj < 4; nj++) {
        int col = (w & 1) * 64 + nj * 16 + lr;      // head-local col
        a1c[nj] = ag[h * 256 + col];
        a2c[nj] = ag[h * 256 + 128 + col];
    }
    float p1[16], p2[16];
    #pragma unroll
    for (int mi = 0; mi < 4; mi++)
        #pragma unroll
        for (int r = 0; r < 4; r++) {
            float v1 = 0.f, v2 = 0.f;
            #pragma unroll
            for (int nj = 0; nj < 4; nj++) {
                float tv = acc[mi][nj][r];
                v1 += tv * a1c[nj];
                v2 += tv * a2c[nj];
            }
            p1[mi * 4 + r] = v1;
            p2[mi * 4 + r] = v2;
        }
    #pragma unroll
    for (int off = 1; off < 16; off <<= 1)
        #pragma unroll
        for (int i = 0; i < 16; i++) {
            p1[i] += __shfl_xor(p1[i], off, 64);
            p2[i] += __shfl_xor(p2[i], off, 64);
        }
    // stash half-head partials in (reused) LDS, combine across wave pairs
    float* S = (float*)smem;                        // [2][8][64] floats = 4 KB
    if (lr == 0) {
        #pragma unroll
        for (int mi = 0; mi < 4; mi++)
            #pragma unroll
            for (int r = 0; r < 4; r++) {
                int row = mi * 16 + lk * 4 + r;
                S[0 * 512 + w * 64 + row] = p1[mi * 4 + r];
                S[1 * 512 + w * 64 + row] = p2[mi * 4 + r];
            }
    }
    __syncthreads();
    {
        int si = tid >> 8;                          // 0: s1, 1: s2
        int rem = tid & 255;
        int hh = rem >> 6, row = rem & 63;
        int grw = m0 + row;
        if (grw < MROWS) {
            float v = S[si * 512 + (hh * 2) * 64 + row]
                    + S[si * 512 + (hh * 2 + 1) * 64 + row];
            (si ? s2g : s1g)[(long)grw * 4 + hh] = v;
        }
    }
}

// ---- kernel 3: fused edge pass: score + leaky + exp + dst-sorted scatter
//      + GLOBAL Z via 8 fp32 atomicAdds (zreduce folded in). ----
__global__ void edgescatter_kernel(const int* __restrict__ ei, const float* __restrict__ s1,
                                   const float* __restrict__ s2, int* __restrict__ cursor,
                                   int* __restrict__ srcs, float* __restrict__ pw,
                                   float* __restrict__ Zsum) {
    int e = blockIdx.x * 256 + threadIdx.x;
    int tid = threadIdx.x;
    float v[8] = {0.f, 0.f, 0.f, 0.f, 0.f, 0.f, 0.f, 0.f};
    if (e < En) {
        int src = ei[e], dst = ei[En + e];
        #pragma unroll
        for (int b = 0; b < Bn; b++) {
            float4 v1 = *(const float4*)(s1 + ((long)b * Nn + src) * 4);
            float4 v2 = *(const float4*)(s2 + ((long)b * Nn + dst) * 4);
            float s;
            s = v1.x + v2.x; s = s > 0.f ? s : 0.2f * s; v[b * 4 + 0] = __expf(s);
            s = v1.y + v2.y; s = s > 0.f ? s : 0.2f * s; v[b * 4 + 1] = __expf(s);
            s = v1.z + v2.z; s = s > 0.f ? s : 0.2f * s; v[b * 4 + 2] = __expf(s);
            s = v1.w + v2.w; s = s > 0.f ? s : 0.2f * s; v[b * 4 + 3] = __expf(s);
        }
        int pos = atomicAdd(&cursor[dst], 1);
        srcs[pos] = src;
        *(float4*)(pw + (long)pos * 4)        = make_float4(v[0], v[1], v[2], v[3]);
        *(float4*)(pw + ((long)En + pos) * 4) = make_float4(v[4], v[5], v[6], v[7]);
    }
    #pragma unroll
    for (int off = 1; off < 64; off <<= 1)
        #pragma unroll
        for (int i = 0; i < 8; i++)
            v[i] += __shfl_xor(v[i], off, 64);
    __shared__ float red[4][8];
    if ((tid & 63) == 0)
        #pragma unroll
        for (int i = 0; i < 8; i++)
            red[tid >> 6][i] = v[i];
    __syncthreads();
    if (tid < 8)
        atomicAdd(&Zsum[tid], red[0][tid] + red[1][tid] + red[2][tid] + red[3][tid]);
}

// ---- kernel 4: aggregation, one WAVE per (batch,node): 128 thr = 2 waves.
//      uint4 t-loads, masked 4-wide unroll, LN via pure 64-lane shfl. ----
__launch_bounds__(128)
__global__ void agg_kernel(const u16* __restrict__ t, const int* __restrict__ srcs,
                           const float* __restrict__ pw, const float* __restrict__ Zsum,
                           const int* __restrict__ offs,
                           const float* __restrict__ gamma, const float* __restrict__ beta,
                           float* __restrict__ out) {
    int tid = threadIdx.x;
    int b = tid >> 6;                    // wave 0: batch 0, wave 1: batch 1
    int l = tid & 63;                    // lane owns cols 8*l .. 8*l+7
    int n = blockIdx.x;
    int h = l >> 4;                      // head = (8*l)/128
    int j0 = offs[n], j1 = offs[n + 1];
    const float* pwb = pw + (long)b * En * 4;
    const u16* tb = t + (long)b * Nn * 512;
    float a0 = 0.f, a1 = 0.f, a2 = 0.f, a3 = 0.f;
    float a4 = 0.f, a5 = 0.f, a6 = 0.f, a7 = 0.f;
    for (int j = j0; j < j1; j += 4) {
        int  jj0 = j,     jj1 = j + 1,  jj2 = j + 2,  jj3 = j + 3;
        bool k1 = jj1 < j1, k2 = jj2 < j1, k3 = jj3 < j1;
        int  i1 = k1 ? jj1 : j0, i2 = k2 ? jj2 : j0, i3 = k3 ? jj3 : j0;
        int s0 = srcs[jj0], s1i = srcs[i1], s2i = srcs[i2], s3i = srcs[i3];
        float w0 = pwb[(long)jj0 * 4 + h];
        float w1 = k1 ? pwb[(long)i1 * 4 + h] : 0.f;
        float w2 = k2 ? pwb[(long)i2 * 4 + h] : 0.f;
        float w3 = k3 ? pwb[(long)i3 * 4 + h] : 0.f;
        uint4 r0 = *(const uint4*)(tb + (long)s0 * 512 + l * 8);
        uint4 r1 = *(const uint4*)(tb + (long)s1i * 512 + l * 8);
        uint4 r2 = *(const uint4*)(tb + (long)s2i * 512 + l * 8);
        uint4 r3 = *(const uint4*)(tb + (long)s3i * 512 + l * 8);
        a0 += w0 * bflo(r0.x) + w1 * bflo(r1.x) + w2 * bflo(r2.x) + w3 * bflo(r3.x);
        a1 += w0 * bfhi(r0.x) + w1 * bfhi(r1.x) + w2 * bfhi(r2.x) + w3 * bfhi(r3.x);
        a2 += w0 * bflo(r0.y) + w1 * bflo(r1.y) + w2 * bflo(r2.y) + w3 * bflo(r3.y);
        a3 += w0 * bfhi(r0.y) + w1 * bfhi(r1.y) + w2 * bfhi(r2.y) + w3 * bfhi(r3.y);
        a4 += w0 * bflo(r0.z) + w1 * bflo(r1.z) + w2 * bflo(r2.z) + w3 * bflo(r3.z);
        a5 += w0 * bfhi(r0.z) + w1 * bfhi(r1.z) + w2 * bfhi(r2.z) + w3 * bfhi(r3.z);
        a6 += w0 * bflo(r0.w) + w1 * bflo(r1.w) + w2 * bflo(r2.w) + w3 * bflo(r3.w);
        a7 += w0 * bfhi(r0.w) + w1 * bfhi(r1.w) + w2 * bfhi(r2.w) + w3 * bfhi(r3.w);
    }
    float invz = 1.0f / Zsum[b * 4 + h];
    a0 *= invz; a1 *= invz; a2 *= invz; a3 *= invz;
    a4 *= invz; a5 *= invz; a6 *= invz; a7 *= invz;
    float s  = a0 + a1 + a2 + a3 + a4 + a5 + a6 + a7;
    float ss = a0 * a0 + a1 * a1 + a2 * a2 + a3 * a3
             + a4 * a4 + a5 * a5 + a6 * a6 + a7 * a7;
    #pragma unroll
    for (int off = 1; off < 64; off <<= 1) {
        s  += __shfl_xor(s, off, 64);
        ss += __shfl_xor(ss, off, 64);
    }
    float mean = s * (1.0f / 512.0f);
    float var = ss * (1.0f / 512.0f) - mean * mean;
    var = var < 0.f ? 0.f : var;
    float scale = rsqrtf(var + LNEPS);
    int c = l * 8;
    float4 g0 = *(const float4*)(gamma + c);
    float4 g1 = *(const float4*)(gamma + c + 4);
    float4 b0 = *(const float4*)(beta + c);
    float4 b1 = *(const float4*)(beta + c + 4);
    float4 o0, o1;
    o0.x = (a0 - mean) * scale * g0.x + b0.x;
    o0.y = (a1 - mean) * scale * g0.y + b0.y;
    o0.z = (a2 - mean) * scale * g0.z + b0.z;
    o0.w = (a3 - mean) * scale * g0.w + b0.w;
    o1.x = (a4 - mean) * scale * g1.x + b1.x;
    o1.y = (a5 - mean) * scale * g1.y + b1.y;
    o1.z = (a6 - mean) * scale * g1.z + b1.z;
    o1.w = (a7 - mean) * scale * g1.w + b1.w;
    float* op = out + ((long)b * Nn + n) * 512 + c;
    *(float4*)(op)     = o0;
    *(float4*)(op + 4) = o1;
}

extern "C" void kernel_launch(void* const* d_in, const int* in_sizes, int n_in,
                              void* d_out, int out_size, void* d_ws, size_t ws_size,
                              hipStream_t stream) {
    const float* x     = (const float*)d_in[0];
    const int*   ei    = (const int*)d_in[1];   // (2,E) int32
    const float* W     = (const float*)d_in[2];
    const float* a     = (const float*)d_in[3];
    const float* gamma = (const float*)d_in[4];
    const float* beta  = (const float*)d_in[5];
    float* out = (float*)d_out;

    char* ws = (char*)d_ws;
    size_t off = 0;
    auto alloc = [&](size_t bytes) -> void* {
        void* ptr = ws + off;
        off = (off + bytes + 255) & ~(size_t)255;
        return ptr;
    };
    u16*   wbt    = (u16*)alloc((size_t)512 * 512 * 2);        // 0.5 MB
    u16*   t      = (u16*)alloc((size_t)MPAD * 512 * 2);       // 61.5 MB
    float* s1     = (float*)alloc((size_t)MROWS * 4 * 4);
    float* s2     = (float*)alloc((size_t)MROWS * 4 * 4);
    float* pw     = (float*)alloc((size_t)Bn * En * 4 * 4);    // dst-sorted numerators
    float* Zsum   = (float*)alloc(8 * 4);
    int*   deg    = (int*)alloc((size_t)Nn * 4);
    int*   offs   = (int*)alloc((size_t)(Nn + 1) * 4);
    int*   cursor = (int*)alloc((size_t)Nn * 4);
    int*   srcs   = (int*)alloc((size_t)En * 4);

    hipMemsetAsync(deg, 0, (size_t)Nn * 4, stream);
    hipMemsetAsync(Zsum, 0, 8 * 4, stream);

    prep_kernel<<<CVTW_BLKS + EBLK, 256, 0, stream>>>(W, wbt, ei, deg);
    gemm<<<939, 512, 0, stream>>>(x, wbt, a, t, s1, s2, deg, offs, cursor);
    edgescatter_kernel<<<EBLK, 256, 0, stream>>>(ei, s1, s2, cursor, srcs, pw, Zsum);
    agg_kernel<<<Nn, 128, 0, stream>>>(t, srcs, pw, Zsum, offs, gamma, beta, out);
}

// Round 8
// 359.800 us; speedup vs baseline: 1.0433x; 1.0433x over previous
//
#include <hip/hip_runtime.h>
#include <stdint.h>

#define Bn 2
#define Nn 30000
#define En 120000
#define KIN 512
#define Hh 4
#define Dd 128
#define MROWS 60000            // B*N rows
#define MPAD  60032            // 469 * 128
#define LNEPS 1e-5f
#define EBLK 469               // ceil(En/256)

typedef unsigned short u16;
typedef unsigned int   u32;
typedef __attribute__((ext_vector_type(8))) short short8;
typedef __attribute__((ext_vector_type(4))) short bf16x4;
typedef __attribute__((ext_vector_type(4))) float f32x4;

__device__ __forceinline__ u16 f2bf(float f) {
    u32 u = __builtin_bit_cast(u32, f);
    u32 r = u + 0x7FFFu + ((u >> 16) & 1u);
    return (u16)(r >> 16);
}
__device__ __forceinline__ float bflo(u32 u) {
    return __builtin_bit_cast(float, u << 16);
}
__device__ __forceinline__ float bfhi(u32 u) {
    return __builtin_bit_cast(float, u & 0xFFFF0000u);
}
__device__ __forceinline__ void ld16(void* lds, const void* g) {
    __builtin_amdgcn_global_load_lds((const __attribute__((address_space(1))) void*)g,
                                     (__attribute__((address_space(3))) void*)lds, 16, 0, 0);
}

// ---- kernel 1: prep = cvt_w (1024 blocks) + hist (469) ----
#define CVTW_BLKS 1024         // 512*512/256 exactly
__global__ void prep_kernel(const float* __restrict__ W, u16* __restrict__ wbt,
                            const int* __restrict__ ei, int* __restrict__ deg) {
    int blk = blockIdx.x;
    if (blk < CVTW_BLKS) {
        int idx = blk * 256 + threadIdx.x;
        int c = idx >> 9, i = idx & 511;
        int h = c >> 7, d = c & 127;
        wbt[idx] = f2bf(W[h * (KIN * Dd) + i * Dd + d]);
    } else {
        int e = (blk - CVTW_BLKS) * 256 + threadIdx.x;
        if (e < En) atomicAdd(&deg[ei[En + e]], 1);
    }
}

// ---- scan as a device function: 512 threads, exclusive scan of deg[30000].
//      part[] reuses the gemm's LDS block. ----
__device__ void scan512(const int* __restrict__ deg, int* __restrict__ offs,
                        int* __restrict__ cursor, int* __restrict__ part) {
    int tid = threadIdx.x;
    const int CH = 59;                 // 512*59 = 30208 >= Nn
    int start = tid * CH;
    int s = 0;
    for (int i = 0; i < CH; i++) {
        int n = start + i;
        if (n < Nn) s += deg[n];
    }
    part[tid] = s;
    __syncthreads();
    for (int off = 1; off < 512; off <<= 1) {
        int xv = (tid >= off) ? part[tid - off] : 0;
        __syncthreads();
        part[tid] += xv;
        __syncthreads();
    }
    int run = part[tid] - s;
    for (int i = 0; i < CH; i++) {
        int n = start + i;
        if (n < Nn) {
            offs[n] = run;
            cursor[n] = run;
            run += deg[n];
        }
    }
    if (tid == 511) offs[Nn] = part[511];
}

// ---- kernel 2: GEMM t = x(f32) * wbt^T, fused cvt (r6 structure, BM=128).
//      THIS ROUND'S CHANGE: swapped-operand MFMA (mfma(bv, af)) transposes
//      the C/D map so each lane holds 4 CONSECUTIVE output cols:
//        row = m0 + wrM + mi*16 + lr,  cols = wc + nj*16 + lk*4 + (0..3)
//      -> C-write via per-wave-private LDS bounce (b64 writes, b128 reads,
//         16 coalesced dwordx4 global stores) instead of 128 scalar u16
//         stores/lane (the one component shared by ALL six flat variants).
//      s1/s2 also simplifies: per-lane rows, 2-hop shfl over lk. ----
#define A_LDS (2 * 128 * 32)
#define B_LDS (2 * 512 * 32)
__launch_bounds__(512)
__global__ void gemm(const float* __restrict__ x, const u16* __restrict__ wbt,
                     const float* __restrict__ ag, u16* __restrict__ t,
                     float* __restrict__ s1g, float* __restrict__ s2g,
                     const int* __restrict__ deg, int* __restrict__ offs,
                     int* __restrict__ cursor) {
    __shared__ __align__(16) u16 smem[A_LDS + B_LDS];   // 80 KB exactly
    if (blockIdx.x == 0) { scan512(deg, offs, cursor, (int*)smem); return; }
    u16* As0 = smem;
    u16* As1 = smem + 128 * 32;
    u16* Bs0 = smem + A_LDS;
    u16* Bs1 = smem + A_LDS + 512 * 32;
    const int tid = threadIdx.x;
    const int m0 = (blockIdx.x - 1) * 128;          // tiles 0..468
    const int w = tid >> 6, l = tid & 63;
    const int lr = l & 15, lk = l >> 4;
    const int wrM = (w >> 2) * 64;                  // wave row base
    const int h = w & 3;                            // wave head
    const int wc = h * 128;                         // wave col base
    // swizzled ds_read offsets (u16 units): byte ^= ((row&6)<<3) on the 16B slot
    const int swz = (lk * 8) ^ ((lr & 6) << 2);
    int aoff[4], boff[8];
    #pragma unroll
    for (int mi = 0; mi < 4; mi++) aoff[mi] = (wrM + mi * 16 + lr) * 32 + swz;
    #pragma unroll
    for (int nj = 0; nj < 8; nj++) boff[nj] = (wc + nj * 16 + lr) * 32 + swz;

    // A source: thread covers row = tid>>2 (clamped), k-chunk = tid&3 (8 f32)
    const int arow_u = m0 + (tid >> 2);
    const int arow = arow_u < MROWS ? arow_u : (MROWS - 1);   // pad-row clamp
    const float* xsrc = x + (long)arow * KIN + (tid & 3) * 8;
    // swizzled A ds_write address (u16 units), constant across steps
    const int awr = (tid >> 2) * 32 + (((tid & 3) * 8) ^ (((tid >> 2) & 6) << 2));

    // B source: pre-swizzled global (inverse of read swizzle; involution)
    const int grow = tid >> 2, gslot = tid & 3;
    const int gsw = (gslot * 8) ^ ((grow & 6) << 2);
    const u16* bgsrc = wbt + (long)grow * KIN + gsw;   // chunk i = i*512+tid
    f32x4 acc[4][8] = {};
    float4 a0A, a1A, a0B, a1B;                         // 2 static x-reg sets

#define LOADX(R0, R1, KS)                                           \
    {                                                               \
        R0 = *(const float4*)(xsrc + (KS) * 32);                    \
        R1 = *(const float4*)(xsrc + (KS) * 32 + 4);                \
    }
#define CVTW(BUF, R0, R1)                                           \
    {                                                               \
        short8 o;                                                   \
        o[0] = (short)f2bf(R0.x); o[1] = (short)f2bf(R0.y);         \
        o[2] = (short)f2bf(R0.z); o[3] = (short)f2bf(R0.w);         \
        o[4] = (short)f2bf(R1.x); o[5] = (short)f2bf(R1.y);         \
        o[6] = (short)f2bf(R1.z); o[7] = (short)f2bf(R1.w);         \
        *(short8*)&(BUF)[awr] = o;                                  \
    }

    auto STAGEB = [&](u16* Bb, int k0) {
        #pragma unroll
        for (int i = 0; i < 4; i++)
            ld16(Bb + ((long)(i * 512 + tid)) * 8, bgsrc + (long)i * 128 * KIN + k0);
    };

    // prologue: x(0)->setA, x(1)->setB, B(0) staged, A(0) written
    LOADX(a0A, a1A, 0);
    LOADX(a0B, a1B, 1);
    STAGEB(Bs0, 0);
    CVTW(As0, a0A, a1A);
    __syncthreads();

    #pragma unroll
    for (int t16 = 0; t16 < 16; t16++) {
        u16* Acur = (t16 & 1) ? As1 : As0;
        u16* Bcur = (t16 & 1) ? Bs1 : Bs0;
        u16* Anext = (t16 & 1) ? As0 : As1;
        u16* Bnext = (t16 & 1) ? Bs0 : Bs1;
        if (t16 < 14) {                     // x(t+2) into the just-freed set
            if (t16 & 1) { LOADX(a0B, a1B, t16 + 2); }
            else         { LOADX(a0A, a1A, t16 + 2); }
        }
        if (t16 < 15) STAGEB(Bnext, (t16 + 1) * 32);
        short8 af[4];
        #pragma unroll
        for (int mi = 0; mi < 4; mi++) af[mi] = *(const short8*)&Acur[aoff[mi]];
        #pragma unroll
        for (int nj = 0; nj < 8; nj++) {
            short8 bv = *(const short8*)&Bcur[boff[nj]];
            #pragma unroll
            for (int mi = 0; mi < 4; mi++)
                acc[mi][nj] = __builtin_amdgcn_mfma_f32_16x16x32_bf16(
                    bv, af[mi], acc[mi][nj], 0, 0, 0);   // SWAPPED operands
        }
        if (t16 < 15) {                     // write A(t+1) from set ((t+1)&1)
            if (t16 & 1) { CVTW(Anext, a0A, a1A); }
            else         { CVTW(Anext, a0B, a1B); }
        }
        __syncthreads();    // drains staging + protects buffer reuse
    }
#undef LOADX
#undef CVTW

    // ---- s1/s2 (swapped layout): lane owns rows mi*16+lr; cols in-lane ----
    float p1[4] = {0.f, 0.f, 0.f, 0.f}, p2[4] = {0.f, 0.f, 0.f, 0.f};
    #pragma unroll
    for (int nj = 0; nj < 8; nj++) {
        float4 c1 = *(const float4*)(ag + h * 256 + nj * 16 + lk * 4);
        float4 c2 = *(const float4*)(ag + h * 256 + 128 + nj * 16 + lk * 4);
        #pragma unroll
        for (int mi = 0; mi < 4; mi++) {
            p1[mi] += acc[mi][nj][0] * c1.x + acc[mi][nj][1] * c1.y
                    + acc[mi][nj][2] * c1.z + acc[mi][nj][3] * c1.w;
            p2[mi] += acc[mi][nj][0] * c2.x + acc[mi][nj][1] * c2.y
                    + acc[mi][nj][2] * c2.z + acc[mi][nj][3] * c2.w;
        }
    }
    #pragma unroll
    for (int off = 16; off < 64; off <<= 1)
        #pragma unroll
        for (int mi = 0; mi < 4; mi++) {
            p1[mi] += __shfl_xor(p1[mi], off, 64);
            p2[mi] += __shfl_xor(p2[mi], off, 64);
        }
    if (lk == 0) {
        #pragma unroll
        for (int mi = 0; mi < 4; mi++) {
            int row = m0 + wrM + mi * 16 + lr;
            if (row < MROWS) {
                s1g[(long)row * 4 + h] = p1[mi];
                s2g[(long)row * 4 + h] = p2[mi];
            }
        }
    }

    // ---- C-write: per-wave-private LDS bounce -> coalesced dwordx4 stores.
    //      T = 64 rows x 80 u16 (pad 80: b128 read 2-way bank-free).
    //      8 waves x 10240 B = 80 KB exactly (A/B buffers are dead). ----
    {
        u16* T = smem + w * 5120;
        const int l8 = l & 7, li = l >> 3;
        #pragma unroll
        for (int h2 = 0; h2 < 2; h2++) {
            #pragma unroll
            for (int mi = 0; mi < 4; mi++)
                #pragma unroll
                for (int nj4 = 0; nj4 < 4; nj4++) {
                    int nj = h2 * 4 + nj4;
                    bf16x4 o;
                    o[0] = (short)f2bf(acc[mi][nj][0]);
                    o[1] = (short)f2bf(acc[mi][nj][1]);
                    o[2] = (short)f2bf(acc[mi][nj][2]);
                    o[3] = (short)f2bf(acc[mi][nj][3]);
                    *(bf16x4*)&T[(mi * 16 + lr) * 80 + nj4 * 16 + lk * 4] = o;
                }
            #pragma unroll
            for (int i = 0; i < 8; i++) {
                int rowL = i * 8 + li;
                short8 v = *(const short8*)&T[rowL * 80 + l8 * 8];
                *(short8*)(t + (long)(m0 + wrM + rowL) * 512 + wc + h2 * 64 + l8 * 8) = v;
            }
        }
    }
}

// ---- kernel 3: fused edge pass: score + leaky + exp + dst-sorted scatter
//      + GLOBAL Z via 8 fp32 atomicAdds (zreduce folded in). ----
__global__ void edgescatter_kernel(const int* __restrict__ ei, const float* __restrict__ s1,
                                   const float* __restrict__ s2, int* __restrict__ cursor,
                                   int* __restrict__ srcs, float* __restrict__ pw,
                                   float* __restrict__ Zsum) {
    int e = blockIdx.x * 256 + threadIdx.x;
    int tid = threadIdx.x;
    float v[8] = {0.f, 0.f, 0.f, 0.f, 0.f, 0.f, 0.f, 0.f};
    if (e < En) {
        int src = ei[e], dst = ei[En + e];
        #pragma unroll
        for (int b = 0; b < Bn; b++) {
            float4 v1 = *(const float4*)(s1 + ((long)b * Nn + src) * 4);
            float4 v2 = *(const float4*)(s2 + ((long)b * Nn + dst) * 4);
            float s;
            s = v1.x + v2.x; s = s > 0.f ? s : 0.2f * s; v[b * 4 + 0] = __expf(s);
            s = v1.y + v2.y; s = s > 0.f ? s : 0.2f * s; v[b * 4 + 1] = __expf(s);
            s = v1.z + v2.z; s = s > 0.f ? s : 0.2f * s; v[b * 4 + 2] = __expf(s);
            s = v1.w + v2.w; s = s > 0.f ? s : 0.2f * s; v[b * 4 + 3] = __expf(s);
        }
        int pos = atomicAdd(&cursor[dst], 1);
        srcs[pos] = src;
        *(float4*)(pw + (long)pos * 4)        = make_float4(v[0], v[1], v[2], v[3]);
        *(float4*)(pw + ((long)En + pos) * 4) = make_float4(v[4], v[5], v[6], v[7]);
    }
    #pragma unroll
    for (int off = 1; off < 64; off <<= 1)
        #pragma unroll
        for (int i = 0; i < 8; i++)
            v[i] += __shfl_xor(v[i], off, 64);
    __shared__ float red[4][8];
    if ((tid & 63) == 0)
        #pragma unroll
        for (int i = 0; i < 8; i++)
            red[tid >> 6][i] = v[i];
    __syncthreads();
    if (tid < 8)
        atomicAdd(&Zsum[tid], red[0][tid] + red[1][tid] + red[2][tid] + red[3][tid]);
}

// ---- kernel 4: aggregation, one WAVE per (batch,node): 128 thr = 2 waves.
//      uint4 t-loads, masked 4-wide unroll, LN via pure 64-lane shfl. ----
__launch_bounds__(128)
__global__ void agg_kernel(const u16* __restrict__ t, const int* __restrict__ srcs,
                           const float* __restrict__ pw, const float* __restrict__ Zsum,
                           const int* __restrict__ offs,
                           const float* __restrict__ gamma, const float* __restrict__ beta,
                           float* __restrict__ out) {
    int tid = threadIdx.x;
    int b = tid >> 6;                    // wave 0: batch 0, wave 1: batch 1
    int l = tid & 63;                    // lane owns cols 8*l .. 8*l+7
    int n = blockIdx.x;
    int h = l >> 4;                      // head = (8*l)/128
    int j0 = offs[n], j1 = offs[n + 1];
    const float* pwb = pw + (long)b * En * 4;
    const u16* tb = t + (long)b * Nn * 512;
    float a0 = 0.f, a1 = 0.f, a2 = 0.f, a3 = 0.f;
    float a4 = 0.f, a5 = 0.f, a6 = 0.f, a7 = 0.f;
    for (int j = j0; j < j1; j += 4) {
        int  jj0 = j,     jj1 = j + 1,  jj2 = j + 2,  jj3 = j + 3;
        bool k1 = jj1 < j1, k2 = jj2 < j1, k3 = jj3 < j1;
        int  i1 = k1 ? jj1 : jj0, i2 = k2 ? jj2 : jj0, i3 = k3 ? jj3 : jj0;
        int s0 = srcs[jj0], s1i = srcs[i1], s2i = srcs[i2], s3i = srcs[i3];
        float w0 = pwb[(long)jj0 * 4 + h];
        float w1 = k1 ? pwb[(long)i1 * 4 + h] : 0.f;
        float w2 = k2 ? pwb[(long)i2 * 4 + h] : 0.f;
        float w3 = k3 ? pwb[(long)i3 * 4 + h] : 0.f;
        uint4 r0 = *(const uint4*)(tb + (long)s0 * 512 + l * 8);
        uint4 r1 = *(const uint4*)(tb + (long)s1i * 512 + l * 8);
        uint4 r2 = *(const uint4*)(tb + (long)s2i * 512 + l * 8);
        uint4 r3 = *(const uint4*)(tb + (long)s3i * 512 + l * 8);
        a0 += w0 * bflo(r0.x) + w1 * bflo(r1.x) + w2 * bflo(r2.x) + w3 * bflo(r3.x);
        a1 += w0 * bfhi(r0.x) + w1 * bfhi(r1.x) + w2 * bfhi(r2.x) + w3 * bfhi(r3.x);
        a2 += w0 * bflo(r0.y) + w1 * bflo(r1.y) + w2 * bflo(r2.y) + w3 * bflo(r3.y);
        a3 += w0 * bfhi(r0.y) + w1 * bfhi(r1.y) + w2 * bfhi(r2.y) + w3 * bfhi(r3.y);
        a4 += w0 * bflo(r0.z) + w1 * bflo(r1.z) + w2 * bflo(r2.z) + w3 * bflo(r3.z);
        a5 += w0 * bfhi(r0.z) + w1 * bfhi(r1.z) + w2 * bfhi(r2.z) + w3 * bfhi(r3.z);
        a6 += w0 * bflo(r0.w) + w1 * bflo(r1.w) + w2 * bflo(r2.w) + w3 * bflo(r3.w);
        a7 += w0 * bfhi(r0.w) + w1 * bfhi(r1.w) + w2 * bfhi(r2.w) + w3 * bfhi(r3.w);
    }
    float invz = 1.0f / Zsum[b * 4 + h];
    a0 *= invz; a1 *= invz; a2 *= invz; a3 *= invz;
    a4 *= invz; a5 *= invz; a6 *= invz; a7 *= invz;
    float s  = a0 + a1 + a2 + a3 + a4 + a5 + a6 + a7;
    float ss = a0 * a0 + a1 * a1 + a2 * a2 + a3 * a3
             + a4 * a4 + a5 * a5 + a6 * a6 + a7 * a7;
    #pragma unroll
    for (int off = 1; off < 64; off <<= 1) {
        s  += __shfl_xor(s, off, 64);
        ss += __shfl_xor(ss, off, 64);
    }
    float mean = s * (1.0f / 512.0f);
    float var = ss * (1.0f / 512.0f) - mean * mean;
    var = var < 0.f ? 0.f : var;
    float scale = rsqrtf(var + LNEPS);
    int c = l * 8;
    float4 g0 = *(const float4*)(gamma + c);
    float4 g1 = *(const float4*)(gamma + c + 4);
    float4 b0 = *(const float4*)(beta + c);
    float4 b1 = *(const float4*)(beta + c + 4);
    float4 o0, o1;
    o0.x = (a0 - mean) * scale * g0.x + b0.x;
    o0.y = (a1 - mean) * scale * g0.y + b0.y;
    o0.z = (a2 - mean) * scale * g0.z + b0.z;
    o0.w = (a3 - mean) * scale * g0.w + b0.w;
    o1.x = (a4 - mean) * scale * g1.x + b1.x;
    o1.y = (a5 - mean) * scale * g1.y + b1.y;
    o1.z = (a6 - mean) * scale * g1.z + b1.z;
    o1.w = (a7 - mean) * scale * g1.w + b1.w;
    float* op = out + ((long)b * Nn + n) * 512 + c;
    *(float4*)(op)     = o0;
    *(float4*)(op + 4) = o1;
}

extern "C" void kernel_launch(void* const* d_in, const int* in_sizes, int n_in,
                              void* d_out, int out_size, void* d_ws, size_t ws_size,
                              hipStream_t stream) {
    const float* x     = (const float*)d_in[0];
    const int*   ei    = (const int*)d_in[1];   // (2,E) int32
    const float* W     = (const float*)d_in[2];
    const float* a     = (const float*)d_in[3];
    const float* gamma = (const float*)d_in[4];
    const float* beta  = (const float*)d_in[5];
    float* out = (float*)d_out;

    char* ws = (char*)d_ws;
    size_t off = 0;
    auto alloc = [&](size_t bytes) -> void* {
        void* ptr = ws + off;
        off = (off + bytes + 255) & ~(size_t)255;
        return ptr;
    };
    u16*   wbt    = (u16*)alloc((size_t)512 * 512 * 2);        // 0.5 MB
    u16*   t      = (u16*)alloc((size_t)MPAD * 512 * 2);       // 61.5 MB
    float* s1     = (float*)alloc((size_t)MROWS * 4 * 4);
    float* s2     = (float*)alloc((size_t)MROWS * 4 * 4);
    float* pw     = (float*)alloc((size_t)Bn * En * 4 * 4);    // dst-sorted numerators
    float* Zsum   = (float*)alloc(8 * 4);
    int*   deg    = (int*)alloc((size_t)Nn * 4);
    int*   offs   = (int*)alloc((size_t)(Nn + 1) * 4);
    int*   cursor = (int*)alloc((size_t)Nn * 4);
    int*   srcs   = (int*)alloc((size_t)En * 4);

    hipMemsetAsync(deg, 0, (size_t)Nn * 4, stream);
    hipMemsetAsync(Zsum, 0, 8 * 4, stream);

    prep_kernel<<<CVTW_BLKS + EBLK, 256, 0, stream>>>(W, wbt, ei, deg);
    gemm<<<470, 512, 0, stream>>>(x, wbt, a, t, s1, s2, deg, offs, cursor);
    edgescatter_kernel<<<EBLK, 256, 0, stream>>>(ei, s1, s2, cursor, srcs, pw, Zsum);
    agg_kernel<<<Nn, 128, 0, stream>>>(t, srcs, pw, Zsum, offs, gamma, beta, out);
}